// Round 8
// baseline (831.554 us; speedup 1.0000x reference)
//
#include <hip/hip_runtime.h>
#include <hip/hip_bf16.h>
#include <stdint.h>

#define ENC_DIM 2048
#define ATT_DIM 512
#define BATCH   256
#define NPIX    196
#define MROWS   (BATCH*NPIX)          // 50176 = 784 * 64 exactly
#define CTX_OFF (BATCH*ENC_DIM)       // context, then alpha

typedef __attribute__((ext_vector_type(8))) short  short8;
typedef __attribute__((ext_vector_type(4))) float  f32x4;

__device__ __forceinline__ uint32_t f2bf(float x) {
    union { float f; uint32_t u; } v; v.f = x;
    return (v.u + 0x7FFFu + ((v.u >> 16) & 1u)) >> 16;
}

__device__ __forceinline__ short8 cvt8(f32x4 x, f32x4 y) {
    short8 r;
    r[0] = (short)f2bf(x[0]); r[1] = (short)f2bf(x[1]);
    r[2] = (short)f2bf(x[2]); r[3] = (short)f2bf(x[3]);
    r[4] = (short)f2bf(y[0]); r[5] = (short)f2bf(y[1]);
    r[6] = (short)f2bf(y[2]); r[7] = (short)f2bf(y[3]);
    return r;
}

// ---------------------------------------------------------------------------
// Kernel 0: pack W_enc (fp32 [2048][512]) -> bf16 k-major Wt[a][k]
// ---------------------------------------------------------------------------
__global__ __launch_bounds__(256) void pack_wt(const float* __restrict__ W,
                                               unsigned short* __restrict__ Wt) {
    const int i  = blockIdx.x * 256 + threadIdx.x;   // 0 .. 131071
    const int a  = i >> 8;                            // 0..511
    const int kg = i & 255;                           // 0..255
    short8 v;
#pragma unroll
    for (int j = 0; j < 8; ++j)
        v[j] = (short)f2bf(W[(size_t)(kg * 8 + j) * 512 + a]);
    *(short8*)(Wt + (size_t)a * 2048 + kg * 8) = v;
}

// ---------------------------------------------------------------------------
// Kernel 1: att2p[b][a] = hidden[b,:] @ W_dec[:,a] + b_dec[a] + b_enc[a]
// ---------------------------------------------------------------------------
__global__ __launch_bounds__(256) void att2_kernel(const float* __restrict__ hidden,
                                                   const float* __restrict__ Wdec,
                                                   const float* __restrict__ bdec,
                                                   const float* __restrict__ benc,
                                                   float* __restrict__ att2p) {
    __shared__ float h[512];
    const int b   = blockIdx.x;
    const int tid = threadIdx.x;
    h[tid]       = hidden[(size_t)b * 512 + tid];
    h[tid + 256] = hidden[(size_t)b * 512 + tid + 256];
    __syncthreads();
    float acc0 = bdec[tid]       + benc[tid];
    float acc1 = bdec[tid + 256] + benc[tid + 256];
#pragma unroll 4
    for (int k = 0; k < 512; ++k) {
        const float hk = h[k];
        acc0 = fmaf(hk, Wdec[(size_t)k * 512 + tid],       acc0);
        acc1 = fmaf(hk, Wdec[(size_t)k * 512 + tid + 256], acc1);
    }
    att2p[(size_t)b * 512 + tid]       = acc0;
    att2p[(size_t)b * 512 + tid + 256] = acc1;
}

// ---------------------------------------------------------------------------
// Kernel 2: scores. 784 blocks x 512 thr (8 waves). NO LDS / NO barriers in
// the K-loop. D[a][pix]: A-operand = Wt (k-major bf16, L2-resident), loaded
// direct; B-operand = enc rows, loaded direct as f32 and converted in-reg.
// Wave tile: 128 atts x 32 pixels (ag = w&3, pg = w>>2). 64 k-steps.
// Epilogue: relu+wf dot in regs, shfl reduce over a, LDS-atomic combine.
// ---------------------------------------------------------------------------
__global__ __launch_bounds__(512, 3) void score_kernel(const float* __restrict__ enc,
                                                       const unsigned short* __restrict__ Wt,
                                                       const float* __restrict__ att2p,
                                                       const float* __restrict__ Wfull,
                                                       float* __restrict__ scores) {
    __shared__ float lds_att2[2][ATT_DIM];
    __shared__ float lds_wf[ATT_DIM];
    __shared__ float lds_sc[64];

    const int tid = threadIdx.x;
    const int w   = tid >> 6;
    const int l   = tid & 63;
    const int ag  = w & 3;          // a-group: atts [128ag, 128ag+128)
    const int pg  = w >> 2;         // pixel-group: pixels [32pg, 32pg+32)
    const int m0  = blockIdx.x * 64;
    const int b0  = m0 / NPIX;
    const int b1  = (m0 + 63) / NPIX;

    lds_att2[0][tid] = att2p[(size_t)b0 * ATT_DIM + tid];
    lds_att2[1][tid] = att2p[(size_t)b1 * ATT_DIM + tid];
    lds_wf[tid] = Wfull[tid];
    if (tid < 64) lds_sc[tid] = 0.0f;
    __syncthreads();

    const int lr = l & 15;          // fragment row/col lane index
    const int ko = l >> 4;          // k-octet 0..3

    // A (Wt) base: a = ag*128 + af*16 + lr ; k = kb + ko*8
    const unsigned short* pA = Wt + ((size_t)(ag * 128 + lr)) * 2048 + ko * 8;
    // B (enc) bases for pf=0,1: pix = pg*32 + pf*16 + lr
    const float* pB0 = enc + ((size_t)(m0 + pg * 32 + lr)) * ENC_DIM + ko * 8;
    const float* pB1 = pB0 + (size_t)16 * ENC_DIM;

    f32x4 acc[8][2];
#pragma unroll
    for (int i = 0; i < 8; ++i) {
        acc[i][0] = (f32x4){0.f, 0.f, 0.f, 0.f};
        acc[i][1] = (f32x4){0.f, 0.f, 0.f, 0.f};
    }

    // prefetch B for step 0
    f32x4 b0a = *(const f32x4*)(pB0);
    f32x4 b0b = *(const f32x4*)(pB0 + 4);
    f32x4 b1a = *(const f32x4*)(pB1);
    f32x4 b1b = *(const f32x4*)(pB1 + 4);

#pragma unroll 1
    for (int s = 0; s < 64; ++s) {
        const short8 bf0 = cvt8(b0a, b0b);
        const short8 bf1 = cvt8(b1a, b1b);
        if (s < 63) {             // prefetch next step's B (HBM stream)
            const int off = (s + 1) * 32;
            b0a = *(const f32x4*)(pB0 + off);
            b0b = *(const f32x4*)(pB0 + off + 4);
            b1a = *(const f32x4*)(pB1 + off);
            b1b = *(const f32x4*)(pB1 + off + 4);
        }
        const unsigned short* pAs = pA + s * 32;
#pragma unroll
        for (int af = 0; af < 8; ++af) {
            const short8 avf = *(const short8*)(pAs + (size_t)af * 32768);
            acc[af][0] = __builtin_amdgcn_mfma_f32_16x16x32_bf16(avf, bf0, acc[af][0], 0, 0, 0);
            acc[af][1] = __builtin_amdgcn_mfma_f32_16x16x32_bf16(avf, bf1, acc[af][1], 0, 0, 0);
        }
    }

    // ---- epilogue: bias + relu + dot(Wf), reduce over atts ----
#pragma unroll
    for (int pf = 0; pf < 2; ++pf) {
        const int pix = pg * 32 + pf * 16 + lr;
        const int sel = ((m0 + pix) >= (b0 + 1) * NPIX) ? 1 : 0;
        float sp = 0.0f;
#pragma unroll
        for (int af = 0; af < 8; ++af) {
#pragma unroll
            for (int r = 0; r < 4; ++r) {
                const int a = ag * 128 + af * 16 + ko * 4 + r;
                float v = acc[af][pf][r] + lds_att2[sel][a];
                v = fmaxf(v, 0.0f);
                sp = fmaf(v, lds_wf[a], sp);
            }
        }
        sp += __shfl_xor(sp, 16);
        sp += __shfl_xor(sp, 32);
        if (l < 16) atomicAdd(&lds_sc[pg * 32 + pf * 16 + l], sp);
    }
    __syncthreads();
    if (tid < 64) scores[m0 + tid] = lds_sc[tid];
}

// ---------------------------------------------------------------------------
// Kernel 3: softmax + context. grid = B x 4 e-quarters; 256 thr;
// thread owns float4 of e, covers half the pixels; LDS combine.
// ---------------------------------------------------------------------------
__global__ __launch_bounds__(256) void ctx_kernel(const float* __restrict__ enc,
                                                  const float* __restrict__ scores,
                                                  float* __restrict__ out) {
    __shared__ float salpha[NPIX];
    __shared__ float red[8];
    __shared__ float partial[512];
    const int tid  = threadIdx.x;
    const int lane = tid & 63;
    const int wid  = tid >> 6;
    const int b    = blockIdx.x >> 2;
    const int eq   = blockIdx.x & 3;

    const float sv = (tid < NPIX) ? scores[(size_t)b * NPIX + tid] : -1e30f;
    float mx = sv;
#pragma unroll
    for (int m = 32; m >= 1; m >>= 1) mx = fmaxf(mx, __shfl_xor(mx, m));
    if (lane == 0) red[wid] = mx;
    __syncthreads();
    if (tid == 0) red[4] = fmaxf(fmaxf(red[0], red[1]), fmaxf(red[2], red[3]));
    __syncthreads();
    const float bm = red[4];
    const float ex = (tid < NPIX) ? __expf(sv - bm) : 0.0f;
    float sm = ex;
#pragma unroll
    for (int m = 32; m >= 1; m >>= 1) sm += __shfl_xor(sm, m);
    if (lane == 0) red[wid] = sm;
    __syncthreads();
    if (tid == 0) red[5] = red[0] + red[1] + red[2] + red[3];
    __syncthreads();
    const float inv = 1.0f / red[5];
    if (tid < NPIX) {
        const float av = ex * inv;
        salpha[tid] = av;
        if (eq == 0) out[CTX_OFF + (size_t)b * NPIX + tid] = av;
    }
    __syncthreads();

    const int l128 = tid & 127;
    const int ph   = tid >> 7;
    const float* ep = enc + (size_t)b * NPIX * ENC_DIM + eq * 512 + l128 * 4;
    f32x4 acc = (f32x4){0.f, 0.f, 0.f, 0.f};
#pragma unroll 4
    for (int n = ph; n < NPIX; n += 2) {
        const float al = salpha[n];
        f32x4 v = *(const f32x4*)(ep + (size_t)n * ENC_DIM);
        acc += v * al;
    }
    if (ph == 1) *(f32x4*)(partial + l128 * 4) = acc;
    __syncthreads();
    if (ph == 0) {
        f32x4 o = acc + *(const f32x4*)(partial + l128 * 4);
        *(f32x4*)(out + (size_t)b * ENC_DIM + eq * 512 + l128 * 4) = o;
    }
}

// ---------------------------------------------------------------------------
extern "C" void kernel_launch(void* const* d_in, const int* in_sizes, int n_in,
                              void* d_out, int out_size, void* d_ws, size_t ws_size,
                              hipStream_t stream) {
    const float* enc    = (const float*)d_in[0];
    const float* hidden = (const float*)d_in[1];
    const float* Wenc   = (const float*)d_in[2];
    const float* benc   = (const float*)d_in[3];
    const float* Wdec   = (const float*)d_in[4];
    const float* bdec   = (const float*)d_in[5];
    const float* Wfull  = (const float*)d_in[6];
    // d_in[7] = b_full: softmax-shift-invariant, unused.
    float* out = (float*)d_out;

    unsigned short* Wt    = (unsigned short*)d_ws;                              // 2 MB
    float*          att2p = (float*)((char*)d_ws + (2u << 20));                 // 512 KB
    float*          scores= (float*)((char*)d_ws + (2u << 20) + (512u << 10));  // 200 KB

    pack_wt     <<<512, 256, 0, stream>>>(Wenc, Wt);
    att2_kernel <<<BATCH, 256, 0, stream>>>(hidden, Wdec, bdec, benc, att2p);
    score_kernel<<<MROWS / 64, 512, 0, stream>>>(enc, Wt, att2p, Wfull, scores);
    ctx_kernel  <<<BATCH * 4, 256, 0, stream>>>(enc, scores, out);
}

// Round 9
// 372.129 us; speedup vs baseline: 2.2346x; 2.2346x over previous
//
#include <hip/hip_runtime.h>
#include <hip/hip_bf16.h>
#include <stdint.h>

#define ENC_DIM 2048
#define ATT_DIM 512
#define BATCH   256
#define NPIX    196
#define MROWS   (BATCH*NPIX)          // 50176 = 784 * 64
#define CTX_OFF (BATCH*ENC_DIM)       // context, then alpha
#define KC      64                    // K per chunk
#define NCH     (ENC_DIM/KC)          // 32
#define NPAIR   784                   // row-tiles of 64

typedef __attribute__((ext_vector_type(8))) short  short8;
typedef __attribute__((ext_vector_type(4))) float  f32x4;

__device__ __forceinline__ uint32_t f2bf(float x) {
    union { float f; uint32_t u; } v; v.f = x;
    return (v.u + 0x7FFFu + ((v.u >> 16) & 1u)) >> 16;
}

__device__ __forceinline__ uint4 pack8(f32x4 a0, f32x4 a1) {
    uint4 u;
    u.x = f2bf(a0[0]) | (f2bf(a0[1]) << 16);
    u.y = f2bf(a0[2]) | (f2bf(a0[3]) << 16);
    u.z = f2bf(a1[0]) | (f2bf(a1[1]) << 16);
    u.w = f2bf(a1[2]) | (f2bf(a1[3]) << 16);
    return u;
}

// ---------------------------------------------------------------------------
// Kernel 0: pack W_enc (fp32 [2048][512]) -> bf16 Wp[(k/8)*512 + n][8]
// ---------------------------------------------------------------------------
__global__ __launch_bounds__(256) void pack_wenc(const float* __restrict__ W,
                                                 unsigned short* __restrict__ Wp) {
    const int i  = blockIdx.x * 256 + threadIdx.x;   // 0 .. 131071
    const int n  = i & 511;
    const int kg = i >> 9;
    short8 v;
#pragma unroll
    for (int j = 0; j < 8; ++j)
        v[j] = (short)f2bf(W[(size_t)(kg * 8 + j) * 512 + n]);
    *(short8*)(Wp + (size_t)i * 8) = v;
}

// ---------------------------------------------------------------------------
// Kernel 1: att2p[b][a] = hidden[b,:] @ W_dec[:,a] + b_dec[a] + b_enc[a]
// ---------------------------------------------------------------------------
__global__ __launch_bounds__(256) void att2_kernel(const float* __restrict__ hidden,
                                                   const float* __restrict__ Wdec,
                                                   const float* __restrict__ bdec,
                                                   const float* __restrict__ benc,
                                                   float* __restrict__ att2p) {
    __shared__ float h[512];
    const int b   = blockIdx.x;
    const int tid = threadIdx.x;
    h[tid]       = hidden[(size_t)b * 512 + tid];
    h[tid + 256] = hidden[(size_t)b * 512 + tid + 256];
    __syncthreads();
    float acc0 = bdec[tid]       + benc[tid];
    float acc1 = bdec[tid + 256] + benc[tid + 256];
#pragma unroll 4
    for (int k = 0; k < 512; ++k) {
        const float hk = h[k];
        acc0 = fmaf(hk, Wdec[(size_t)k * 512 + tid],       acc0);
        acc1 = fmaf(hk, Wdec[(size_t)k * 512 + tid + 256], acc1);
    }
    att2p[(size_t)b * 512 + tid]       = acc0;
    att2p[(size_t)b * 512 + tid + 256] = acc1;
}

// ---------------------------------------------------------------------------
// Kernel 1b: zero the scores accumulator (196 blocks x 256)
// ---------------------------------------------------------------------------
__global__ __launch_bounds__(256) void zero_scores(float* __restrict__ scores) {
    scores[blockIdx.x * 256 + threadIdx.x] = 0.0f;
}

// ---------------------------------------------------------------------------
// Kernel 2: scores. 1568 blocks x 256 thr (4 waves!). Block = 64 rows x 256
// atts (half = bid/784 -> same-XCD pairing since 784%8==0). A: reg-staged
// fp32->bf16 dbuf LDS, swizzle byte^=(row&7)<<4; B direct from L2; raw
// lgkm-only barrier per chunk. 3 blocks/CU -> decorrelated barrier convoys.
// Cross-block score combine via global atomicAdd.
// ---------------------------------------------------------------------------
__global__ __launch_bounds__(256, 3) void score_kernel(const float* __restrict__ enc,
                                                       const unsigned short* __restrict__ Wp,
                                                       const float* __restrict__ att2p,
                                                       const float* __restrict__ Wfull,
                                                       float* __restrict__ scores) {
    __shared__ __align__(16) unsigned char ldsA[2][64 * KC * 2];   // 2 x 8 KB
    __shared__ float lds_att2[2][ATT_DIM];
    __shared__ float lds_wf[ATT_DIM];
    __shared__ float lds_sc[64];

    const int tid  = threadIdx.x;
    const int w    = tid >> 6;          // 0..3
    const int l    = tid & 63;
    const int lr   = l & 15;
    const int kq   = l >> 4;
    const int pair = blockIdx.x % NPAIR;
    const int half = blockIdx.x / NPAIR;   // 0 or 1 (784 apart -> same XCD)
    const int m0   = pair * 64;
    const int b0   = m0 / NPIX;
    const int b1   = (m0 + 63) / NPIX;

    lds_att2[0][tid]       = att2p[(size_t)b0 * ATT_DIM + tid];
    lds_att2[0][tid + 256] = att2p[(size_t)b0 * ATT_DIM + tid + 256];
    lds_att2[1][tid]       = att2p[(size_t)b1 * ATT_DIM + tid];
    lds_att2[1][tid + 256] = att2p[(size_t)b1 * ATT_DIM + tid + 256];
    lds_wf[tid]       = Wfull[tid];
    lds_wf[tid + 256] = Wfull[tid + 256];
    if (tid < 64) lds_sc[tid] = 0.0f;

    // ---- A staging geometry: thread -> (row 0..63, 16-float k-span) ----
    const int arow = tid >> 2;
    const int aj   = tid & 3;
    const int key  = arow & 7;
    const int aw0  = arow * 128 + (((aj * 2)     ^ key) << 4);
    const int aw1  = arow * 128 + (((aj * 2 + 1) ^ key) << 4);
    const float* aG = enc + (size_t)(m0 + arow) * ENC_DIM + aj * 16;

    // ---- A fragment read geometry ----
    int ard[4];
#pragma unroll
    for (int mf = 0; mf < 4; ++mf) ard[mf] = (mf * 16 + lr) * 128;
    const int akey = l & 7;             // (mf*16+lr)&7 == l&7

    // ---- B global offsets (shorts) ----
    int boff[4];
#pragma unroll
    for (int nf = 0; nf < 4; ++nf)
        boff[nf] = (kq * 512 + half * 256 + (w << 6) + (nf << 4) + lr) * 8;

    f32x4 acc[4][4];
#pragma unroll
    for (int i = 0; i < 4; ++i)
#pragma unroll
        for (int j = 0; j < 4; ++j)
            acc[i][j] = (f32x4){0.f, 0.f, 0.f, 0.f};

    // ---- prologue: stage chunk 0 -> buffer 0; preload chunk 1 to regs ----
    {
        f32x4 s0 = *(const f32x4*)(aG);
        f32x4 s1 = *(const f32x4*)(aG + 4);
        f32x4 s2 = *(const f32x4*)(aG + 8);
        f32x4 s3 = *(const f32x4*)(aG + 12);
        *(uint4*)(ldsA[0] + aw0) = pack8(s0, s1);
        *(uint4*)(ldsA[0] + aw1) = pack8(s2, s3);
    }
    f32x4 rc0 = *(const f32x4*)(aG + KC);
    f32x4 rc1 = *(const f32x4*)(aG + KC + 4);
    f32x4 rc2 = *(const f32x4*)(aG + KC + 8);
    f32x4 rc3 = *(const f32x4*)(aG + KC + 12);
    __syncthreads();

#define STEP(S, BV)                                                            \
    {                                                                          \
        _Pragma("unroll")                                                      \
        for (int mf = 0; mf < 4; ++mf) {                                       \
            short8 af = *(const short8*)(ldsR + ard[mf] +                      \
                                         ((((S) * 4 + kq) ^ akey) << 4));      \
            _Pragma("unroll")                                                  \
            for (int nf = 0; nf < 4; ++nf)                                     \
                acc[mf][nf] = __builtin_amdgcn_mfma_f32_16x16x32_bf16(         \
                    af, BV[nf], acc[mf][nf], 0, 0, 0);                         \
        }                                                                      \
    }

#pragma unroll 1
    for (int c = 0; c < NCH; ++c) {
        const int p = c & 1;
        const unsigned char* ldsR = ldsA[p];
        const unsigned short* bC  = Wp + (size_t)c * 32768;
        // B loads first (oldest in vmem queue -> counted waits leave A alone)
        short8 b0v[4], b1v[4];
#pragma unroll
        for (int nf = 0; nf < 4; ++nf) b0v[nf] = *(const short8*)(bC + boff[nf]);
#pragma unroll
        for (int nf = 0; nf < 4; ++nf) b1v[nf] = *(const short8*)(bC + boff[nf] + 16384);
        // issue A loads for chunk c+2
        const int cc = (c + 2 < NCH) ? (c + 2) : (NCH - 1);
        f32x4 rn0 = *(const f32x4*)(aG + cc * KC);
        f32x4 rn1 = *(const f32x4*)(aG + cc * KC + 4);
        f32x4 rn2 = *(const f32x4*)(aG + cc * KC + 8);
        f32x4 rn3 = *(const f32x4*)(aG + cc * KC + 12);
        STEP(0, b0v)
        if (c + 1 < NCH) {
            *(uint4*)(ldsA[p ^ 1] + aw0) = pack8(rc0, rc1);
            *(uint4*)(ldsA[p ^ 1] + aw1) = pack8(rc2, rc3);
        }
        STEP(1, b1v)
        // raw barrier: order LDS only; vmem prefetch stays in flight
        asm volatile("s_waitcnt lgkmcnt(0)" ::: "memory");
        __builtin_amdgcn_s_barrier();
        rc0 = rn0; rc1 = rn1; rc2 = rn2; rc3 = rn3;
    }
#undef STEP

    // ---- epilogue: bias + relu + dot(Wf), reduce to per-row partials ----
#pragma unroll
    for (int mf = 0; mf < 4; ++mf) {
#pragma unroll
        for (int reg = 0; reg < 4; ++reg) {
            const int row = mf * 16 + (kq << 2) + reg;
            const int sel = ((m0 + row) >= (b0 + 1) * NPIX) ? 1 : 0;
            float sv = 0.0f;
#pragma unroll
            for (int nf = 0; nf < 4; ++nf) {
                const int col = half * 256 + (w << 6) + (nf << 4) + lr;
                float v = acc[mf][nf][reg] + lds_att2[sel][col];
                v = fmaxf(v, 0.0f);
                sv = fmaf(v, lds_wf[col], sv);
            }
            sv += __shfl_xor(sv, 8);
            sv += __shfl_xor(sv, 4);
            sv += __shfl_xor(sv, 2);
            sv += __shfl_xor(sv, 1);
            if (lr == 0) atomicAdd(&lds_sc[row], sv);
        }
    }
    __syncthreads();
    if (tid < 64) atomicAdd(&scores[m0 + tid], lds_sc[tid]);
}

// ---------------------------------------------------------------------------
// Kernel 3: softmax + context. grid = B x 4 e-quarters; 256 thr.
// ---------------------------------------------------------------------------
__global__ __launch_bounds__(256) void ctx_kernel(const float* __restrict__ enc,
                                                  const float* __restrict__ scores,
                                                  float* __restrict__ out) {
    __shared__ float salpha[NPIX];
    __shared__ float red[8];
    __shared__ float partial[512];
    const int tid  = threadIdx.x;
    const int lane = tid & 63;
    const int wid  = tid >> 6;
    const int b    = blockIdx.x >> 2;
    const int eq   = blockIdx.x & 3;

    const float sv = (tid < NPIX) ? scores[(size_t)b * NPIX + tid] : -1e30f;
    float mx = sv;
#pragma unroll
    for (int m = 32; m >= 1; m >>= 1) mx = fmaxf(mx, __shfl_xor(mx, m));
    if (lane == 0) red[wid] = mx;
    __syncthreads();
    if (tid == 0) red[4] = fmaxf(fmaxf(red[0], red[1]), fmaxf(red[2], red[3]));
    __syncthreads();
    const float bm = red[4];
    const float ex = (tid < NPIX) ? __expf(sv - bm) : 0.0f;
    float sm = ex;
#pragma unroll
    for (int m = 32; m >= 1; m >>= 1) sm += __shfl_xor(sm, m);
    if (lane == 0) red[wid] = sm;
    __syncthreads();
    if (tid == 0) red[5] = red[0] + red[1] + red[2] + red[3];
    __syncthreads();
    const float inv = 1.0f / red[5];
    if (tid < NPIX) {
        const float av = ex * inv;
        salpha[tid] = av;
        if (eq == 0) out[CTX_OFF + (size_t)b * NPIX + tid] = av;
    }
    __syncthreads();

    const int l128 = tid & 127;
    const int ph   = tid >> 7;
    const float* ep = enc + (size_t)b * NPIX * ENC_DIM + eq * 512 + l128 * 4;
    f32x4 acc = (f32x4){0.f, 0.f, 0.f, 0.f};
#pragma unroll 4
    for (int n = ph; n < NPIX; n += 2) {
        const float al = salpha[n];
        f32x4 v = *(const f32x4*)(ep + (size_t)n * ENC_DIM);
        acc += v * al;
    }
    if (ph == 1) *(f32x4*)(partial + l128 * 4) = acc;
    __syncthreads();
    if (ph == 0) {
        f32x4 o = acc + *(const f32x4*)(partial + l128 * 4);
        *(f32x4*)(out + (size_t)b * ENC_DIM + eq * 512 + l128 * 4) = o;
    }
}

// ---------------------------------------------------------------------------
extern "C" void kernel_launch(void* const* d_in, const int* in_sizes, int n_in,
                              void* d_out, int out_size, void* d_ws, size_t ws_size,
                              hipStream_t stream) {
    const float* enc    = (const float*)d_in[0];
    const float* hidden = (const float*)d_in[1];
    const float* Wenc   = (const float*)d_in[2];
    const float* benc   = (const float*)d_in[3];
    const float* Wdec   = (const float*)d_in[4];
    const float* bdec   = (const float*)d_in[5];
    const float* Wfull  = (const float*)d_in[6];
    // d_in[7] = b_full: softmax-shift-invariant, unused.
    float* out = (float*)d_out;

    unsigned short* Wp    = (unsigned short*)d_ws;                              // 2 MB
    float*          att2p = (float*)((char*)d_ws + (2u << 20));                 // 512 KB
    float*          scores= (float*)((char*)d_ws + (2u << 20) + (512u << 10));  // 200 KB

    pack_wenc   <<<512, 256, 0, stream>>>(Wenc, Wp);
    att2_kernel <<<BATCH, 256, 0, stream>>>(hidden, Wdec, bdec, benc, att2p);
    zero_scores <<<MROWS / 256, 256, 0, stream>>>(scores);
    score_kernel<<<2 * NPAIR, 256, 0, stream>>>(enc, Wp, att2p, Wfull, scores);
    ctx_kernel  <<<BATCH * 4, 256, 0, stream>>>(enc, scores, out);
}

// Round 11
// 317.994 us; speedup vs baseline: 2.6150x; 1.1702x over previous
//
#include <hip/hip_runtime.h>
#include <hip/hip_bf16.h>
#include <stdint.h>

#define ENC_DIM 2048
#define ATT_DIM 512
#define BATCH   256
#define NPIX    196
#define MROWS   (BATCH*NPIX)          // 50176 = 392 * 128
#define CTX_OFF (BATCH*ENC_DIM)       // context, then alpha
#define BK      32                    // K per chunk
#define NCH     (ENC_DIM/BK)          // 64
#define NTILE   392                   // 128-row tiles

typedef __attribute__((ext_vector_type(8))) short  short8;
typedef __attribute__((ext_vector_type(4))) float  f32x4;

__device__ __forceinline__ uint32_t f2bf(float x) {
    union { float f; uint32_t u; } v; v.f = x;
    return (v.u + 0x7FFFu + ((v.u >> 16) & 1u)) >> 16;
}

// fp32 pair-of-quads -> 8 bf16 via HW packed convert (RNE)
__device__ __forceinline__ short8 cvt_frag(f32x4 a, f32x4 b) {
    union { uint4 u; short8 s; } r;
    asm("v_cvt_pk_bf16_f32 %0, %1, %2" : "=v"(r.u.x) : "v"(a[0]), "v"(a[1]));
    asm("v_cvt_pk_bf16_f32 %0, %1, %2" : "=v"(r.u.y) : "v"(a[2]), "v"(a[3]));
    asm("v_cvt_pk_bf16_f32 %0, %1, %2" : "=v"(r.u.z) : "v"(b[0]), "v"(b[1]));
    asm("v_cvt_pk_bf16_f32 %0, %1, %2" : "=v"(r.u.w) : "v"(b[2]), "v"(b[3]));
    return r.s;
}

__device__ __forceinline__ void gll16(const float* g, void* l) {
    __builtin_amdgcn_global_load_lds(
        (const __attribute__((address_space(1))) unsigned int*)g,
        (__attribute__((address_space(3))) unsigned int*)l, 16, 0, 0);
}

// ---------------------------------------------------------------------------
// Kernel 0: pack W_enc (fp32 [2048][512]) -> bf16 Wp[(k/8)*512 + n][8]
// ---------------------------------------------------------------------------
__global__ __launch_bounds__(256) void pack_wenc(const float* __restrict__ W,
                                                 unsigned short* __restrict__ Wp) {
    const int i  = blockIdx.x * 256 + threadIdx.x;   // 0 .. 131071
    const int n  = i & 511;
    const int kg = i >> 9;
    short8 v;
#pragma unroll
    for (int j = 0; j < 8; ++j)
        v[j] = (short)f2bf(W[(size_t)(kg * 8 + j) * 512 + n]);
    *(short8*)(Wp + (size_t)i * 8) = v;
}

// ---------------------------------------------------------------------------
// Kernel 1: att2p[b][a] = hidden[b,:] @ W_dec[:,a] + b_dec[a] + b_enc[a]
// ---------------------------------------------------------------------------
__global__ __launch_bounds__(256) void att2_kernel(const float* __restrict__ hidden,
                                                   const float* __restrict__ Wdec,
                                                   const float* __restrict__ bdec,
                                                   const float* __restrict__ benc,
                                                   float* __restrict__ att2p) {
    __shared__ float h[512];
    const int b   = blockIdx.x;
    const int tid = threadIdx.x;
    h[tid]       = hidden[(size_t)b * 512 + tid];
    h[tid + 256] = hidden[(size_t)b * 512 + tid + 256];
    __syncthreads();
    float acc0 = bdec[tid]       + benc[tid];
    float acc1 = bdec[tid + 256] + benc[tid + 256];
#pragma unroll 4
    for (int k = 0; k < 512; ++k) {
        const float hk = h[k];
        acc0 = fmaf(hk, Wdec[(size_t)k * 512 + tid],       acc0);
        acc1 = fmaf(hk, Wdec[(size_t)k * 512 + tid + 256], acc1);
    }
    att2p[(size_t)b * 512 + tid]       = acc0;
    att2p[(size_t)b * 512 + tid + 256] = acc1;
}

__global__ __launch_bounds__(256) void zero_scores(float* __restrict__ scores) {
    scores[blockIdx.x * 256 + threadIdx.x] = 0.0f;
}

// ---------------------------------------------------------------------------
// Kernel 2: scores. 1568 blocks x 256 thr (4 waves, 2 row-halves x 2
// col-halves of a 128x128 tile). Grid = 392 row-tiles x 4 col-quarters
// (quarters of one tile grouped on the same XCD -> A panel L2 reuse).
// A: fp32 via global_load_lds (w16), source pre-swizzled (involution
//    j^=(row&7)), LDS linear; bf16 conversion at frag-read (v_cvt_pk).
// B: direct from L2 (Wp). One __syncthreads per BK=32 chunk (m97 form).
// ---------------------------------------------------------------------------
__global__ __launch_bounds__(256, 3) void score_kernel(const float* __restrict__ enc,
                                                       const unsigned short* __restrict__ Wp,
                                                       const float* __restrict__ att2p,
                                                       const float* __restrict__ Wfull,
                                                       float* __restrict__ scores) {
    __shared__ __align__(16) unsigned char ldsA[2][128 * BK * 4];  // 2 x 16 KB fp32
    __shared__ float lds_att2[2][ATT_DIM];
    __shared__ float lds_wf[ATT_DIM];
    __shared__ float lds_sc[128];

    const int tid = threadIdx.x;
    const int w   = tid >> 6;          // 0..3
    const int l   = tid & 63;
    const int lr  = l & 15;
    const int kq  = l >> 4;            // 0..3
    const int h   = w >> 1;            // row-half
    const int ch  = w & 1;             // col-half (64 cols each)

    // decode: 4 col-quarters of each tile adjacent on one XCD
    const int xcd  = blockIdx.x & 7;
    const int idx  = blockIdx.x >> 3;  // 0..195
    const int lt   = idx >> 2;         // 0..48
    const int q    = idx & 3;          // col-quarter
    const int tile = lt * 8 + xcd;     // 0..391
    const int m0   = tile * 128;
    const int col0 = q * 128;
    const int b0   = m0 / NPIX;
    const int b1   = (m0 + 127) / NPIX;

    lds_att2[0][tid]       = att2p[(size_t)b0 * ATT_DIM + tid];
    lds_att2[0][tid + 256] = att2p[(size_t)b0 * ATT_DIM + tid + 256];
    lds_att2[1][tid]       = att2p[(size_t)b1 * ATT_DIM + tid];
    lds_att2[1][tid + 256] = att2p[(size_t)b1 * ATT_DIM + tid + 256];
    lds_wf[tid]       = Wfull[tid];
    lds_wf[tid + 256] = Wfull[tid + 256];
    if (tid < 128) lds_sc[tid] = 0.0f;

    // ---- A gll geometry: slot S = i*256+tid -> row=S>>3, j=S&7;
    //      source quad = j ^ (row&7) (involution; LDS stays linear)
    int arow[4], asrc[4];
#pragma unroll
    for (int i = 0; i < 4; ++i) {
        const int S = i * 256 + tid;
        arow[i] = S >> 3;
        asrc[i] = ((S & 7) ^ (arow[i] & 7)) << 2;   // float offset in row-chunk
    }

    // ---- A fragment read geometry ----
    const int key  = lr & 7;
    const int so0  = ((2 * kq) ^ key) << 4;          // byte offset of quad 0
    const int so1  = ((2 * kq + 1) ^ key) << 4;
    int ard[4];
#pragma unroll
    for (int mf = 0; mf < 4; ++mf)
        ard[mf] = (h * 64 + mf * 16 + lr) * 128;     // row byte base (128B/row)

    // ---- B global offsets (shorts) ----
    int boff[4];
#pragma unroll
    for (int nf = 0; nf < 4; ++nf)
        boff[nf] = (kq * 512 + col0 + ch * 64 + nf * 16 + lr) * 8;

    f32x4 acc[4][4];
#pragma unroll
    for (int i = 0; i < 4; ++i)
#pragma unroll
        for (int j = 0; j < 4; ++j)
            acc[i][j] = (f32x4){0.f, 0.f, 0.f, 0.f};

    // ---- prologue: gll chunk 0 -> buf 0 ----
#pragma unroll
    for (int i = 0; i < 4; ++i)
        gll16(enc + (size_t)(m0 + arow[i]) * ENC_DIM + asrc[i],
              ldsA[0] + (i * 256 + tid) * 16);
    __syncthreads();

#pragma unroll 1
    for (int c = 0; c < NCH; ++c) {
        const int p = c & 1;
        const unsigned char* ldsR = ldsA[p];
        // B loads for this chunk (issued first: oldest in vmem queue)
        const unsigned short* bC = Wp + (size_t)c * 16384;
        short8 bv[4];
#pragma unroll
        for (int nf = 0; nf < 4; ++nf) bv[nf] = *(const short8*)(bC + boff[nf]);
        // async A staging for chunk c+1 (drained by the barrier)
        if (c + 1 < NCH) {
#pragma unroll
            for (int i = 0; i < 4; ++i)
                gll16(enc + (size_t)(m0 + arow[i]) * ENC_DIM + (c + 1) * BK + asrc[i],
                      ldsA[p ^ 1] + (i * 256 + tid) * 16);
        }
        // compute: 4 A-frags (fp32->bf16 at read) x 4 B-frags
#pragma unroll
        for (int mf = 0; mf < 4; ++mf) {
            f32x4 a0 = *(const f32x4*)(ldsR + ard[mf] + so0);
            f32x4 a1 = *(const f32x4*)(ldsR + ard[mf] + so1);
            const short8 af = cvt_frag(a0, a1);
#pragma unroll
            for (int nf = 0; nf < 4; ++nf)
                acc[mf][nf] = __builtin_amdgcn_mfma_f32_16x16x32_bf16(
                    af, bv[nf], acc[mf][nf], 0, 0, 0);
        }
        __syncthreads();
    }

    // ---- epilogue: bias + relu + dot(Wf), reduce to per-row scores ----
#pragma unroll
    for (int mf = 0; mf < 4; ++mf) {
#pragma unroll
        for (int reg = 0; reg < 4; ++reg) {
            const int row = h * 64 + mf * 16 + kq * 4 + reg;
            const int sel = ((m0 + row) >= (b0 + 1) * NPIX) ? 1 : 0;
            float sv = 0.0f;
#pragma unroll
            for (int nf = 0; nf < 4; ++nf) {
                const int col = col0 + ch * 64 + nf * 16 + lr;
                float v = acc[mf][nf][reg] + lds_att2[sel][col];
                v = fmaxf(v, 0.0f);
                sv = fmaf(v, lds_wf[col], sv);
            }
            sv += __shfl_xor(sv, 8);
            sv += __shfl_xor(sv, 4);
            sv += __shfl_xor(sv, 2);
            sv += __shfl_xor(sv, 1);
            if (lr == 0) atomicAdd(&lds_sc[row], sv);
        }
    }
    __syncthreads();
    if (tid < 128) atomicAdd(&scores[m0 + tid], lds_sc[tid]);
}

// ---------------------------------------------------------------------------
// Kernel 3: softmax + context. grid = B x 4 e-quarters; 256 thr.
// ---------------------------------------------------------------------------
__global__ __launch_bounds__(256) void ctx_kernel(const float* __restrict__ enc,
                                                  const float* __restrict__ scores,
                                                  float* __restrict__ out) {
    __shared__ float salpha[NPIX];
    __shared__ float red[8];
    __shared__ float partial[512];
    const int tid  = threadIdx.x;
    const int lane = tid & 63;
    const int wid  = tid >> 6;
    const int b    = blockIdx.x >> 2;
    const int eq   = blockIdx.x & 3;

    const float sv = (tid < NPIX) ? scores[(size_t)b * NPIX + tid] : -1e30f;
    float mx = sv;
#pragma unroll
    for (int m = 32; m >= 1; m >>= 1) mx = fmaxf(mx, __shfl_xor(mx, m));
    if (lane == 0) red[wid] = mx;
    __syncthreads();
    if (tid == 0) red[4] = fmaxf(fmaxf(red[0], red[1]), fmaxf(red[2], red[3]));
    __syncthreads();
    const float bm = red[4];
    const float ex = (tid < NPIX) ? __expf(sv - bm) : 0.0f;
    float sm = ex;
#pragma unroll
    for (int m = 32; m >= 1; m >>= 1) sm += __shfl_xor(sm, m);
    if (lane == 0) red[wid] = sm;
    __syncthreads();
    if (tid == 0) red[5] = red[0] + red[1] + red[2] + red[3];
    __syncthreads();
    const float inv = 1.0f / red[5];
    if (tid < NPIX) {
        const float av = ex * inv;
        salpha[tid] = av;
        if (eq == 0) out[CTX_OFF + (size_t)b * NPIX + tid] = av;
    }
    __syncthreads();

    const int l128 = tid & 127;
    const int ph   = tid >> 7;
    const float* ep = enc + (size_t)b * NPIX * ENC_DIM + eq * 512 + l128 * 4;
    f32x4 acc = (f32x4){0.f, 0.f, 0.f, 0.f};
#pragma unroll 4
    for (int n = ph; n < NPIX; n += 2) {
        const float al = salpha[n];
        f32x4 v = *(const f32x4*)(ep + (size_t)n * ENC_DIM);
        acc += v * al;
    }
    if (ph == 1) *(f32x4*)(partial + l128 * 4) = acc;
    __syncthreads();
    if (ph == 0) {
        f32x4 o = acc + *(const f32x4*)(partial + l128 * 4);
        *(f32x4*)(out + (size_t)b * ENC_DIM + eq * 512 + l128 * 4) = o;
    }
}

// ---------------------------------------------------------------------------
extern "C" void kernel_launch(void* const* d_in, const int* in_sizes, int n_in,
                              void* d_out, int out_size, void* d_ws, size_t ws_size,
                              hipStream_t stream) {
    const float* enc    = (const float*)d_in[0];
    const float* hidden = (const float*)d_in[1];
    const float* Wenc   = (const float*)d_in[2];
    const float* benc   = (const float*)d_in[3];
    const float* Wdec   = (const float*)d_in[4];
    const float* bdec   = (const float*)d_in[5];
    const float* Wfull  = (const float*)d_in[6];
    // d_in[7] = b_full: softmax-shift-invariant, unused.
    float* out = (float*)d_out;

    unsigned short* Wp    = (unsigned short*)d_ws;                              // 2 MB
    float*          att2p = (float*)((char*)d_ws + (2u << 20));                 // 512 KB
    float*          scores= (float*)((char*)d_ws + (2u << 20) + (512u << 10));  // 200 KB

    pack_wenc   <<<512, 256, 0, stream>>>(Wenc, Wp);
    att2_kernel <<<BATCH, 256, 0, stream>>>(hidden, Wdec, bdec, benc, att2p);
    zero_scores <<<MROWS / 256, 256, 0, stream>>>(scores);
    score_kernel<<<4 * NTILE, 256, 0, stream>>>(enc, Wp, att2p, Wfull, scores);
    ctx_kernel  <<<BATCH * 4, 256, 0, stream>>>(enc, scores, out);
}